// Round 2
// baseline (328.729 us; speedup 1.0000x reference)
//
#include <hip/hip_runtime.h>
#include <stdint.h>

#define GM 4096
#define GN 4096
#define GK 4096
#define BM 128
#define BN 128
#define BK 32
#define QW (GN/8)   /* 512 packed words per k-row */

typedef __attribute__((ext_vector_type(8))) short bf16x8;
typedef __attribute__((ext_vector_type(4))) float f32x4;

// Fused int4-dequant + bf16 MFMA GEMM.
// Tiles: 128x128x32, 256 threads (4 waves, 2x2), each wave 64x64 via 4x4
// mfma_f32_16x16x32_bf16. W^T staged in LDS as Bs[n][k] (k-contiguous so
// B-fragments are ds_read_b128); XOR swizzle k ^= 8*((n>>3)&3) breaks the
// 16-way write conflict down to ~4-way.
__global__ void __launch_bounds__(256) w4a32_gemm(
    const float* __restrict__ A,
    const float* __restrict__ S,
    const uint32_t* __restrict__ Q,
    float* __restrict__ C)
{
  __shared__ __align__(16) ushort As[BM*BK];   // [m][k] bf16, 8 KB
  __shared__ __align__(16) ushort Bs[BN*BK];   // [n][k] bf16 (W^T), 8 KB

  const int tid  = threadIdx.x;
  const int bn   = blockIdx.x;
  const int bm   = blockIdx.y;
  const int m0   = bm*BM;
  const int n0   = bn*BN;

  // B staging: thread handles word column wcol, k rows {2*kpair, 2*kpair+1}
  const int wcol  = tid & 15;
  const int kpair = tid >> 4;      // 0..15

  // compute-phase wave/lane mapping
  const int ln   = tid & 63;
  const int wid  = tid >> 6;
  const int wm   = (wid >> 1) * 64;
  const int wn   = (wid & 1) * 64;
  const int col  = ln & 15;
  const int quad = ln >> 4;

  f32x4 acc[4][4];
  #pragma unroll
  for (int i=0;i<4;++i)
    #pragma unroll
    for (int j=0;j<4;++j)
      acc[i][j] = (f32x4){0.f,0.f,0.f,0.f};

  float sv[8], cv[8];
  float4 spf0, spf1;

  const float*    Abase = A + (size_t)m0 * GK;
  const uint32_t* Qbase = Q + (size_t)(n0>>3) + wcol;

  // prefetch scales for group 0: s[0][n0 + wcol*8 .. +7]
  {
    const float* sp = S + n0 + wcol*8;
    spf0 = *(const float4*)sp;
    spf1 = *(const float4*)(sp + 4);
  }

  // prefetch A-tile / q-words for k0 = 0
  float4 a4[4];
  uint32_t wqa, wqb;
  #pragma unroll
  for (int i=0;i<4;++i) {
    int f = tid + i*256;                       // 1024 float4 per tile
    a4[i] = *(const float4*)(Abase + (size_t)(f>>3)*GK + ((f&7)*4));
  }
  wqa = Qbase[(size_t)(2*kpair)   * QW];
  wqb = Qbase[(size_t)(2*kpair+1) * QW];

  for (int k0 = 0; k0 < GK; k0 += BK) {
    // consume prefetched scales at each group boundary (uniform branch)
    if ((k0 & 127) == 0) {
      sv[0]=spf0.x; sv[1]=spf0.y; sv[2]=spf0.z; sv[3]=spf0.w;
      sv[4]=spf1.x; sv[5]=spf1.y; sv[6]=spf1.z; sv[7]=spf1.w;
      #pragma unroll
      for (int j=0;j<8;++j) cv[j] = -8.0f * sv[j];   // exact (pow2 * s)
    }

    // ---- stage A: fp32 -> bf16 (truncate via v_perm), [m][k] ----
    #pragma unroll
    for (int i=0;i<4;++i) {
      int f = tid + i*256;
      int row = f>>3, c4 = f&7;
      uint32_t x = __builtin_amdgcn_perm(__float_as_uint(a4[i].y),
                                         __float_as_uint(a4[i].x), 0x07060302u);
      uint32_t y = __builtin_amdgcn_perm(__float_as_uint(a4[i].w),
                                         __float_as_uint(a4[i].z), 0x07060302u);
      *(uint2*)(&As[row*BK + c4*4]) = make_uint2(x, y);
    }

    // ---- stage B: dequant 2 k-adjacent words -> 8 (k,k+1) bf16 pairs ----
    {
      const int kk = (2*kpair) ^ (8*(wcol&3));       // XOR bank swizzle
      #pragma unroll
      for (int j=0;j<8;++j) {
        float fa = (float)((wqa >> (4*j)) & 0xFu);   // exact int->f32
        float fb = (float)((wqb >> (4*j)) & 0xFu);
        float wa = fmaf(fa, sv[j], cv[j]);           // (nib-8)*s, 1 rounding
        float wb = fmaf(fb, sv[j], cv[j]);
        uint32_t p = __builtin_amdgcn_perm(__float_as_uint(wb),
                                           __float_as_uint(wa), 0x07060302u);
        int n = wcol*8 + j;
        *(uint32_t*)(&Bs[n*BK + kk]) = p;
      }
    }

    // ---- prefetch next K-step (in flight across barrier + MFMA) ----
    int kn = k0 + BK; if (kn >= GK) kn = 0;
    if ((kn & 127) == 0) {
      const float* sp = S + (size_t)(kn>>7)*GN + n0 + wcol*8;
      spf0 = *(const float4*)sp;
      spf1 = *(const float4*)(sp + 4);
    }
    #pragma unroll
    for (int i=0;i<4;++i) {
      int f = tid + i*256;
      a4[i] = *(const float4*)(Abase + (size_t)(f>>3)*GK + kn + ((f&7)*4));
    }
    wqa = Qbase[(size_t)(kn + 2*kpair)   * QW];
    wqb = Qbase[(size_t)(kn + 2*kpair+1) * QW];

    __syncthreads();

    // ---- compute: 4 A-frags, 4 B-frags, 16 MFMA ----
    bf16x8 af[4], bfr[4];
    #pragma unroll
    for (int t=0;t<4;++t) {
      af[t] = *(const bf16x8*)(&As[(wm + t*16 + col)*BK + quad*8]);
      int n = wn + t*16 + col;
      int kk = (quad*8) ^ (8*((n>>3)&3));
      bfr[t] = *(const bf16x8*)(&Bs[n*BK + kk]);
    }
    #pragma unroll
    for (int mt=0;mt<4;++mt)
      #pragma unroll
      for (int nt=0;nt<4;++nt)
        acc[mt][nt] = __builtin_amdgcn_mfma_f32_16x16x32_bf16(
                          af[mt], bfr[nt], acc[mt][nt], 0, 0, 0);

    __syncthreads();
  }

  // ---- epilogue: C/D layout col=lane&15, row=quad*4+reg (m89) ----
  #pragma unroll
  for (int mt=0;mt<4;++mt) {
    #pragma unroll
    for (int nt=0;nt<4;++nt) {
      #pragma unroll
      for (int r=0;r<4;++r) {
        int row = m0 + wm + mt*16 + quad*4 + r;
        int cn  = n0 + wn + nt*16 + col;
        C[(size_t)row*GN + cn] = acc[mt][nt][r];
      }
    }
  }
}

extern "C" void kernel_launch(void* const* d_in, const int* in_sizes, int n_in,
                              void* d_out, int out_size, void* d_ws, size_t ws_size,
                              hipStream_t stream) {
  const float*    A = (const float*)d_in[0];
  const float*    S = (const float*)d_in[1];
  const uint32_t* Q = (const uint32_t*)d_in[2];
  float*          C = (float*)d_out;
  dim3 grid(GN/BN, GM/BM);   // 32 x 32 = 1024 blocks
  w4a32_gemm<<<grid, dim3(256), 0, stream>>>(A, S, Q, C);
}

// Round 3
// 309.832 us; speedup vs baseline: 1.0610x; 1.0610x over previous
//
#include <hip/hip_runtime.h>
#include <stdint.h>

#define GM 4096
#define GN 4096
#define GK 4096
#define QW (GN/8)   /* 512 packed words per k-row */

typedef __attribute__((ext_vector_type(8))) short bf16x8;
typedef __attribute__((ext_vector_type(4))) float f32x4;

#define AS1 __attribute__((address_space(1)))
#define AS3 __attribute__((address_space(3)))

static __device__ __forceinline__ void glds16(const void* g, void* l) {
  __builtin_amdgcn_global_load_lds((const AS1 uint32_t*)g, (AS3 uint32_t*)l, 16, 0, 0);
}

static __device__ __forceinline__ uint32_t bf16pack(float hi, float lo) {
  // -> (bf16(hi)<<16) | bf16(lo), truncation
  return __builtin_amdgcn_perm(__float_as_uint(hi), __float_as_uint(lo), 0x07060302u);
}

// ---------------- Kernel 1: A fp32 -> bf16 (streaming) ----------------
__global__ void __launch_bounds__(256) a_to_bf16(const float* __restrict__ A,
                                                 ushort* __restrict__ Ab) {
  size_t t = (size_t)blockIdx.x * 256 + threadIdx.x;
  const float4* p = (const float4*)(A + t * 8);
  float4 x = p[0], y = p[1];
  uint4 o;
  o.x = bf16pack(x.y, x.x);
  o.y = bf16pack(x.w, x.z);
  o.z = bf16pack(y.y, y.x);
  o.w = bf16pack(y.w, y.z);
  *(uint4*)(Ab + t * 8) = o;
}

// ------- Kernel 2: int4 dequant -> bf16 W^T [N][K] (LDS transpose) -------
// Tile: 64 k x 128 n. Reads Q coalesced row-wise, writes W^T coalesced
// k-contiguous. XOR octet swizzle (k ^ 8*(w&7)) makes LDS writes
// conflict-free and keeps b128 reads balanced + 16B-aligned.
__global__ void __launch_bounds__(256) w_dequant(const float* __restrict__ S,
                                                 const uint32_t* __restrict__ Q,
                                                 ushort* __restrict__ Wt) {
  __shared__ __align__(16) ushort T[128 * 64];   // 16 KB
  const int tid = threadIdx.x;
  const int n0  = blockIdx.x * 128;
  const int k0  = blockIdx.y * 64;
  const int g   = k0 >> 7;                       // group (64 | 128 -> uniform)

  #pragma unroll
  for (int c = 0; c < 2; ++c) {
    int idx = c * 256 + tid;
    int w   = idx & 15;                          // word col 0..15
    int k   = (idx >> 4) * 2;                    // even k 0..62
    uint32_t q0 = Q[(size_t)(k0 + k)     * QW + (n0 >> 3) + w];
    uint32_t q1 = Q[(size_t)(k0 + k + 1) * QW + (n0 >> 3) + w];
    const float* sp = S + (size_t)g * GN + n0 + w * 8;
    float4 sa = *(const float4*)sp, sb = *(const float4*)(sp + 4);
    float sv[8] = {sa.x, sa.y, sa.z, sa.w, sb.x, sb.y, sb.z, sb.w};
    const int swz = 8 * (w & 7);
    #pragma unroll
    for (int j = 0; j < 8; ++j) {
      float fa = (float)((q0 >> (4 * j)) & 0xFu);    // exact int->f32
      float fb = (float)((q1 >> (4 * j)) & 0xFu);
      float wa = fmaf(fa, sv[j], -8.0f * sv[j]);     // (nib-8)*s, 1 rounding
      float wb = fmaf(fb, sv[j], -8.0f * sv[j]);
      int n = w * 8 + j;
      *(uint32_t*)(&T[n * 64 + (k ^ swz)]) = bf16pack(wb, wa);  // k=wa low
    }
  }
  __syncthreads();
  #pragma unroll
  for (int c = 0; c < 4; ++c) {
    int idx = c * 256 + tid;
    int n = idx >> 3, ko = idx & 7;
    int swz = (n >> 3) & 7;
    uint4 v = *(const uint4*)(&T[n * 64 + 8 * (ko ^ swz)]);
    *(uint4*)(&Wt[(size_t)(n0 + n) * GK + k0 + ko * 8]) = v;
  }
}

// ---------------- Kernel 3: bf16 GEMM, m97 structure ----------------
// 128x128x64 tiles, 256 threads (4 waves 2x2), 4x4 16x16x32 MFMA per wave,
// global_load_lds width=16 staging, 2-barrier K-loop.
__global__ void __launch_bounds__(256) gemm_bf16(const ushort* __restrict__ Ab,
                                                 const ushort* __restrict__ Wt,
                                                 float* __restrict__ C) {
  __shared__ __align__(16) ushort As[128 * 64];  // 16 KB
  __shared__ __align__(16) ushort Bs[128 * 64];  // 16 KB

  const int tid  = threadIdx.x;
  const int m0   = blockIdx.y * 128;
  const int n0   = blockIdx.x * 128;
  const int ln   = tid & 63;
  const int wid  = tid >> 6;
  const int wm   = (wid >> 1) * 64;
  const int wn   = (wid & 1) * 64;
  const int col  = ln & 15;
  const int quad = ln >> 4;
  const int srow = tid >> 3;          // + c*32
  const int scol = (tid & 7) * 8;

  f32x4 acc[4][4];
  #pragma unroll
  for (int i = 0; i < 4; ++i)
    #pragma unroll
    for (int j = 0; j < 4; ++j)
      acc[i][j] = (f32x4){0.f, 0.f, 0.f, 0.f};

  const ushort* Abase = Ab + (size_t)m0 * GK;
  const ushort* Bbase = Wt + (size_t)n0 * GK;

  for (int k0 = 0; k0 < GK; k0 += 64) {
    #pragma unroll
    for (int c = 0; c < 4; ++c)
      glds16(Abase + (size_t)(srow + c * 32) * GK + k0 + scol,
             &As[(c * 256 + tid) * 8]);
    #pragma unroll
    for (int c = 0; c < 4; ++c)
      glds16(Bbase + (size_t)(srow + c * 32) * GK + k0 + scol,
             &Bs[(c * 256 + tid) * 8]);

    __syncthreads();   // drains vmcnt, LDS tiles ready

    #pragma unroll
    for (int kk = 0; kk < 2; ++kk) {
      bf16x8 af[4], bfr[4];
      #pragma unroll
      for (int t = 0; t < 4; ++t) {
        af[t]  = *(const bf16x8*)(&As[(wm + t * 16 + col) * 64 + kk * 32 + quad * 8]);
        bfr[t] = *(const bf16x8*)(&Bs[(wn + t * 16 + col) * 64 + kk * 32 + quad * 8]);
      }
      #pragma unroll
      for (int mt = 0; mt < 4; ++mt)
        #pragma unroll
        for (int nt = 0; nt < 4; ++nt)
          acc[mt][nt] = __builtin_amdgcn_mfma_f32_16x16x32_bf16(
                            af[mt], bfr[nt], acc[mt][nt], 0, 0, 0);
    }

    __syncthreads();   // all reads done before next stage overwrites
  }

  // epilogue: C/D layout col=lane&15, row=quad*4+reg (m89)
  #pragma unroll
  for (int mt = 0; mt < 4; ++mt)
    #pragma unroll
    for (int nt = 0; nt < 4; ++nt)
      #pragma unroll
      for (int r = 0; r < 4; ++r)
        C[(size_t)(m0 + wm + mt * 16 + quad * 4 + r) * GN
          + n0 + wn + nt * 16 + col] = acc[mt][nt][r];
}

// ---------------- Fallback: fused dequant GEMM (round-2 kernel) ----------------
#define BM 128
#define BN 128
#define BK 32

__global__ void __launch_bounds__(256) w4a32_gemm(
    const float* __restrict__ A,
    const float* __restrict__ S,
    const uint32_t* __restrict__ Q,
    float* __restrict__ C)
{
  __shared__ __align__(16) ushort As[BM*BK];
  __shared__ __align__(16) ushort Bs[BN*BK];

  const int tid  = threadIdx.x;
  const int m0   = blockIdx.y*BM;
  const int n0   = blockIdx.x*BN;
  const int wcol  = tid & 15;
  const int kpair = tid >> 4;
  const int ln   = tid & 63;
  const int wid  = tid >> 6;
  const int wm   = (wid >> 1) * 64;
  const int wn   = (wid & 1) * 64;
  const int col  = ln & 15;
  const int quad = ln >> 4;

  f32x4 acc[4][4];
  #pragma unroll
  for (int i=0;i<4;++i)
    #pragma unroll
    for (int j=0;j<4;++j)
      acc[i][j] = (f32x4){0.f,0.f,0.f,0.f};

  float sv[8], cv[8];
  float4 spf0, spf1;

  const float*    Abase = A + (size_t)m0 * GK;
  const uint32_t* Qbase = Q + (size_t)(n0>>3) + wcol;

  {
    const float* sp = S + n0 + wcol*8;
    spf0 = *(const float4*)sp;
    spf1 = *(const float4*)(sp + 4);
  }

  float4 a4[4];
  uint32_t wqa, wqb;
  #pragma unroll
  for (int i=0;i<4;++i) {
    int f = tid + i*256;
    a4[i] = *(const float4*)(Abase + (size_t)(f>>3)*GK + ((f&7)*4));
  }
  wqa = Qbase[(size_t)(2*kpair)   * QW];
  wqb = Qbase[(size_t)(2*kpair+1) * QW];

  for (int k0 = 0; k0 < GK; k0 += BK) {
    if ((k0 & 127) == 0) {
      sv[0]=spf0.x; sv[1]=spf0.y; sv[2]=spf0.z; sv[3]=spf0.w;
      sv[4]=spf1.x; sv[5]=spf1.y; sv[6]=spf1.z; sv[7]=spf1.w;
      #pragma unroll
      for (int j=0;j<8;++j) cv[j] = -8.0f * sv[j];
    }

    #pragma unroll
    for (int i=0;i<4;++i) {
      int f = tid + i*256;
      int row = f>>3, c4 = f&7;
      *(uint2*)(&As[row*BK + c4*4]) =
        make_uint2(bf16pack(a4[i].y, a4[i].x), bf16pack(a4[i].w, a4[i].z));
    }

    {
      const int kk = (2*kpair) ^ (8*(wcol&3));
      #pragma unroll
      for (int j=0;j<8;++j) {
        float fa = (float)((wqa >> (4*j)) & 0xFu);
        float fb = (float)((wqb >> (4*j)) & 0xFu);
        float wa = fmaf(fa, sv[j], cv[j]);
        float wb = fmaf(fb, sv[j], cv[j]);
        int n = wcol*8 + j;
        *(uint32_t*)(&Bs[n*BK + kk]) = bf16pack(wb, wa);
      }
    }

    int kn = k0 + BK; if (kn >= GK) kn = 0;
    if ((kn & 127) == 0) {
      const float* sp = S + (size_t)(kn>>7)*GN + n0 + wcol*8;
      spf0 = *(const float4*)sp;
      spf1 = *(const float4*)(sp + 4);
    }
    #pragma unroll
    for (int i=0;i<4;++i) {
      int f = tid + i*256;
      a4[i] = *(const float4*)(Abase + (size_t)(f>>3)*GK + kn + ((f&7)*4));
    }
    wqa = Qbase[(size_t)(kn + 2*kpair)   * QW];
    wqb = Qbase[(size_t)(kn + 2*kpair+1) * QW];

    __syncthreads();

    bf16x8 af[4], bfr[4];
    #pragma unroll
    for (int t=0;t<4;++t) {
      af[t] = *(const bf16x8*)(&As[(wm + t*16 + col)*BK + quad*8]);
      int n = wn + t*16 + col;
      int kk = (quad*8) ^ (8*((n>>3)&3));
      bfr[t] = *(const bf16x8*)(&Bs[n*BK + kk]);
    }
    #pragma unroll
    for (int mt=0;mt<4;++mt)
      #pragma unroll
      for (int nt=0;nt<4;++nt)
        acc[mt][nt] = __builtin_amdgcn_mfma_f32_16x16x32_bf16(
                          af[mt], bfr[nt], acc[mt][nt], 0, 0, 0);

    __syncthreads();
  }

  #pragma unroll
  for (int mt=0;mt<4;++mt)
    #pragma unroll
    for (int nt=0;nt<4;++nt)
      #pragma unroll
      for (int r=0;r<4;++r)
        C[(size_t)(m0 + wm + mt*16 + quad*4 + r)*GN + n0 + wn + nt*16 + col]
          = acc[mt][nt][r];
}

extern "C" void kernel_launch(void* const* d_in, const int* in_sizes, int n_in,
                              void* d_out, int out_size, void* d_ws, size_t ws_size,
                              hipStream_t stream) {
  const float*    A = (const float*)d_in[0];
  const float*    S = (const float*)d_in[1];
  const uint32_t* Q = (const uint32_t*)d_in[2];
  float*          C = (float*)d_out;

  const size_t need = (size_t)GM * GK * 2 + (size_t)GN * GK * 2;  // 64 MB
  if (ws_size >= need) {
    ushort* Abf = (ushort*)d_ws;                       // [M][K] bf16
    ushort* Wt  = (ushort*)d_ws + (size_t)GM * GK;     // [N][K] bf16 (W^T)
    a_to_bf16<<<dim3(GM * GK / (8 * 256)), dim3(256), 0, stream>>>(A, Abf);
    w_dequant<<<dim3(GN / 128, GK / 64), dim3(256), 0, stream>>>(S, Q, Wt);
    gemm_bf16<<<dim3(GN / 128, GM / 128), dim3(256), 0, stream>>>(Abf, Wt, C);
  } else {
    w4a32_gemm<<<dim3(GN / BN, GM / BM), dim3(256), 0, stream>>>(A, S, Q, C);
  }
}

// Round 4
// 287.289 us; speedup vs baseline: 1.1442x; 1.0785x over previous
//
#include <hip/hip_runtime.h>
#include <stdint.h>

#define GM 4096
#define GN 4096
#define GK 4096
#define QW (GN/8)   /* 512 packed words per k-row */

typedef __attribute__((ext_vector_type(8))) short bf16x8;
typedef __attribute__((ext_vector_type(4))) float f32x4;

#define AS1 __attribute__((address_space(1)))
#define AS3 __attribute__((address_space(3)))

static __device__ __forceinline__ void glds16(const void* g, void* l) {
  __builtin_amdgcn_global_load_lds((const AS1 uint32_t*)g, (AS3 uint32_t*)l, 16, 0, 0);
}

static __device__ __forceinline__ uint32_t bf16pack(float hi, float lo) {
  // -> (bf16(hi)<<16) | bf16(lo), truncation
  return __builtin_amdgcn_perm(__float_as_uint(hi), __float_as_uint(lo), 0x07060302u);
}

// ---------------- Kernel 1: A fp32 -> bf16 (streaming) ----------------
__global__ void __launch_bounds__(256) a_to_bf16(const float* __restrict__ A,
                                                 ushort* __restrict__ Ab) {
  size_t t = (size_t)blockIdx.x * 256 + threadIdx.x;
  const float4* p = (const float4*)(A + t * 8);
  float4 x = p[0], y = p[1];
  uint4 o;
  o.x = bf16pack(x.y, x.x);
  o.y = bf16pack(x.w, x.z);
  o.z = bf16pack(y.y, y.x);
  o.w = bf16pack(y.w, y.z);
  *(uint4*)(Ab + t * 8) = o;
}

// ------- Kernel 2: int4 dequant -> bf16 W^T [N][K] (LDS transpose) -------
__global__ void __launch_bounds__(256) w_dequant(const float* __restrict__ S,
                                                 const uint32_t* __restrict__ Q,
                                                 ushort* __restrict__ Wt) {
  __shared__ __align__(16) ushort T[128 * 64];   // 16 KB
  const int tid = threadIdx.x;
  const int n0  = blockIdx.x * 128;
  const int k0  = blockIdx.y * 64;
  const int g   = k0 >> 7;                       // group (uniform: 64 | 128)

  #pragma unroll
  for (int c = 0; c < 2; ++c) {
    int idx = c * 256 + tid;
    int w   = idx & 15;                          // word col 0..15
    int k   = (idx >> 4) * 2;                    // even k 0..62
    uint32_t q0 = Q[(size_t)(k0 + k)     * QW + (n0 >> 3) + w];
    uint32_t q1 = Q[(size_t)(k0 + k + 1) * QW + (n0 >> 3) + w];
    const float* sp = S + (size_t)g * GN + n0 + w * 8;
    float4 sa = *(const float4*)sp, sb = *(const float4*)(sp + 4);
    float sv[8] = {sa.x, sa.y, sa.z, sa.w, sb.x, sb.y, sb.z, sb.w};
    const int swz = 8 * (w & 7);
    #pragma unroll
    for (int j = 0; j < 8; ++j) {
      float fa = (float)((q0 >> (4 * j)) & 0xFu);    // exact int->f32
      float fb = (float)((q1 >> (4 * j)) & 0xFu);
      float wa = fmaf(fa, sv[j], -8.0f * sv[j]);     // (nib-8)*s, 1 rounding
      float wb = fmaf(fb, sv[j], -8.0f * sv[j]);
      int n = w * 8 + j;
      *(uint32_t*)(&T[n * 64 + (k ^ swz)]) = bf16pack(wb, wa);  // k=wa low
    }
  }
  __syncthreads();
  #pragma unroll
  for (int c = 0; c < 4; ++c) {
    int idx = c * 256 + tid;
    int n = idx >> 3, ko = idx & 7;
    int swz = (n >> 3) & 7;
    uint4 v = *(const uint4*)(&T[n * 64 + 8 * (ko ^ swz)]);
    *(uint4*)(&Wt[(size_t)(n0 + n) * GK + k0 + ko * 8]) = v;
  }
}

// ---------------- Kernel 3: bf16 GEMM, m97 structure + XOR swizzle ----------------
// 128x128x64 tiles, 256 threads (4 waves 2x2), 4x4 16x16x32 MFMA per wave.
// LDS layout: row r, logical k-block kb (8 bf16) stored at kb_phys = kb ^ (r&7).
// Implemented on the write side by permuting the GLOBAL source chunk per lane
// (global_load_lds dest is fixed base+lane*16); each 8-lane octet still covers
// a contiguous 128B row segment -> coalescing preserved. Fragment reads at
// (kb ^ (col&7)) hit all 32 banks evenly -> conflict-free.
__global__ void __launch_bounds__(256) gemm_bf16(const ushort* __restrict__ Ab,
                                                 const ushort* __restrict__ Wt,
                                                 float* __restrict__ C) {
  __shared__ __align__(16) ushort As[128 * 64];  // 16 KB
  __shared__ __align__(16) ushort Bs[128 * 64];  // 16 KB

  const int tid  = threadIdx.x;
  const int m0   = blockIdx.y * 128;
  const int n0   = blockIdx.x * 128;
  const int ln   = tid & 63;
  const int wid  = tid >> 6;
  const int wm   = (wid >> 1) * 64;
  const int wn   = (wid & 1) * 64;
  const int col  = ln & 15;
  const int quad = ln >> 4;
  const int srow = tid >> 3;                               // + c*32
  const int scol = (((tid & 7) ^ (srow & 7)) * 8);         // swizzled source chunk

  f32x4 acc[4][4];
  #pragma unroll
  for (int i = 0; i < 4; ++i)
    #pragma unroll
    for (int j = 0; j < 4; ++j)
      acc[i][j] = (f32x4){0.f, 0.f, 0.f, 0.f};

  const ushort* Abase = Ab + (size_t)m0 * GK;
  const ushort* Bbase = Wt + (size_t)n0 * GK;

  for (int k0 = 0; k0 < GK; k0 += 64) {
    #pragma unroll
    for (int c = 0; c < 4; ++c)
      glds16(Abase + (size_t)(srow + c * 32) * GK + k0 + scol,
             &As[(c * 256 + tid) * 8]);
    #pragma unroll
    for (int c = 0; c < 4; ++c)
      glds16(Bbase + (size_t)(srow + c * 32) * GK + k0 + scol,
             &Bs[(c * 256 + tid) * 8]);

    __syncthreads();   // drains vmcnt, LDS tiles ready

    #pragma unroll
    for (int kk = 0; kk < 2; ++kk) {
      bf16x8 af[4], bfr[4];
      #pragma unroll
      for (int t = 0; t < 4; ++t) {
        const int kbA = (kk * 4 + quad) ^ (col & 7);       // swizzled k-block
        af[t]  = *(const bf16x8*)(&As[(wm + t * 16 + col) * 64 + kbA * 8]);
        bfr[t] = *(const bf16x8*)(&Bs[(wn + t * 16 + col) * 64 + kbA * 8]);
      }
      #pragma unroll
      for (int mt = 0; mt < 4; ++mt)
        #pragma unroll
        for (int nt = 0; nt < 4; ++nt)
          acc[mt][nt] = __builtin_amdgcn_mfma_f32_16x16x32_bf16(
                            af[mt], bfr[nt], acc[mt][nt], 0, 0, 0);
    }

    __syncthreads();   // all reads done before next stage overwrites
  }

  // epilogue: C/D layout col=lane&15, row=quad*4+reg (m89)
  #pragma unroll
  for (int mt = 0; mt < 4; ++mt)
    #pragma unroll
    for (int nt = 0; nt < 4; ++nt)
      #pragma unroll
      for (int r = 0; r < 4; ++r)
        C[(size_t)(m0 + wm + mt * 16 + quad * 4 + r) * GN
          + n0 + wn + nt * 16 + col] = acc[mt][nt][r];
}

// ---------------- Fallback: fused dequant GEMM (round-2 kernel) ----------------
#define BM 128
#define BN 128
#define BK 32

__global__ void __launch_bounds__(256) w4a32_gemm(
    const float* __restrict__ A,
    const float* __restrict__ S,
    const uint32_t* __restrict__ Q,
    float* __restrict__ C)
{
  __shared__ __align__(16) ushort As[BM*BK];
  __shared__ __align__(16) ushort Bs[BN*BK];

  const int tid  = threadIdx.x;
  const int m0   = blockIdx.y*BM;
  const int n0   = blockIdx.x*BN;
  const int wcol  = tid & 15;
  const int kpair = tid >> 4;
  const int ln   = tid & 63;
  const int wid  = tid >> 6;
  const int wm   = (wid >> 1) * 64;
  const int wn   = (wid & 1) * 64;
  const int col  = ln & 15;
  const int quad = ln >> 4;

  f32x4 acc[4][4];
  #pragma unroll
  for (int i=0;i<4;++i)
    #pragma unroll
    for (int j=0;j<4;++j)
      acc[i][j] = (f32x4){0.f,0.f,0.f,0.f};

  float sv[8], cv[8];
  float4 spf0, spf1;

  const float*    Abase = A + (size_t)m0 * GK;
  const uint32_t* Qbase = Q + (size_t)(n0>>3) + wcol;

  {
    const float* sp = S + n0 + wcol*8;
    spf0 = *(const float4*)sp;
    spf1 = *(const float4*)(sp + 4);
  }

  float4 a4[4];
  uint32_t wqa, wqb;
  #pragma unroll
  for (int i=0;i<4;++i) {
    int f = tid + i*256;
    a4[i] = *(const float4*)(Abase + (size_t)(f>>3)*GK + ((f&7)*4));
  }
  wqa = Qbase[(size_t)(2*kpair)   * QW];
  wqb = Qbase[(size_t)(2*kpair+1) * QW];

  for (int k0 = 0; k0 < GK; k0 += BK) {
    if ((k0 & 127) == 0) {
      sv[0]=spf0.x; sv[1]=spf0.y; sv[2]=spf0.z; sv[3]=spf0.w;
      sv[4]=spf1.x; sv[5]=spf1.y; sv[6]=spf1.z; sv[7]=spf1.w;
      #pragma unroll
      for (int j=0;j<8;++j) cv[j] = -8.0f * sv[j];
    }

    #pragma unroll
    for (int i=0;i<4;++i) {
      int f = tid + i*256;
      int row = f>>3, c4 = f&7;
      *(uint2*)(&As[row*BK + c4*4]) =
        make_uint2(bf16pack(a4[i].y, a4[i].x), bf16pack(a4[i].w, a4[i].z));
    }

    {
      const int kk = (2*kpair) ^ (8*(wcol&3));
      #pragma unroll
      for (int j=0;j<8;++j) {
        float fa = (float)((wqa >> (4*j)) & 0xFu);
        float fb = (float)((wqb >> (4*j)) & 0xFu);
        float wa = fmaf(fa, sv[j], cv[j]);
        float wb = fmaf(fb, sv[j], cv[j]);
        int n = wcol*8 + j;
        *(uint32_t*)(&Bs[n*BK + kk]) = bf16pack(wb, wa);
      }
    }

    int kn = k0 + BK; if (kn >= GK) kn = 0;
    if ((kn & 127) == 0) {
      const float* sp = S + (size_t)(kn>>7)*GN + n0 + wcol*8;
      spf0 = *(const float4*)sp;
      spf1 = *(const float4*)(sp + 4);
    }
    #pragma unroll
    for (int i=0;i<4;++i) {
      int f = tid + i*256;
      a4[i] = *(const float4*)(Abase + (size_t)(f>>3)*GK + kn + ((f&7)*4));
    }
    wqa = Qbase[(size_t)(kn + 2*kpair)   * QW];
    wqb = Qbase[(size_t)(kn + 2*kpair+1) * QW];

    __syncthreads();

    bf16x8 af[4], bfr[4];
    #pragma unroll
    for (int t=0;t<4;++t) {
      af[t] = *(const bf16x8*)(&As[(wm + t*16 + col)*BK + quad*8]);
      int n = wn + t*16 + col;
      int kk = (quad*8) ^ (8*((n>>3)&3));
      bfr[t] = *(const bf16x8*)(&Bs[n*BK + kk]);
    }
    #pragma unroll
    for (int mt=0;mt<4;++mt)
      #pragma unroll
      for (int nt=0;nt<4;++nt)
        acc[mt][nt] = __builtin_amdgcn_mfma_f32_16x16x32_bf16(
                          af[mt], bfr[nt], acc[mt][nt], 0, 0, 0);

    __syncthreads();
  }

  #pragma unroll
  for (int mt=0;mt<4;++mt)
    #pragma unroll
    for (int nt=0;nt<4;++nt)
      #pragma unroll
      for (int r=0;r<4;++r)
        C[(size_t)(m0 + wm + mt*16 + quad*4 + r)*GN + n0 + wn + nt*16 + col]
          = acc[mt][nt][r];
}

extern "C" void kernel_launch(void* const* d_in, const int* in_sizes, int n_in,
                              void* d_out, int out_size, void* d_ws, size_t ws_size,
                              hipStream_t stream) {
  const float*    A = (const float*)d_in[0];
  const float*    S = (const float*)d_in[1];
  const uint32_t* Q = (const uint32_t*)d_in[2];
  float*          C = (float*)d_out;

  const size_t need = (size_t)GM * GK * 2 + (size_t)GN * GK * 2;  // 64 MB
  if (ws_size >= need) {
    ushort* Abf = (ushort*)d_ws;                       // [M][K] bf16
    ushort* Wt  = (ushort*)d_ws + (size_t)GM * GK;     // [N][K] bf16 (W^T)
    a_to_bf16<<<dim3(GM * GK / (8 * 256)), dim3(256), 0, stream>>>(A, Abf);
    w_dequant<<<dim3(GN / 128, GK / 64), dim3(256), 0, stream>>>(S, Q, Wt);
    gemm_bf16<<<dim3(GN / 128, GM / 128), dim3(256), 0, stream>>>(Abf, Wt, C);
  } else {
    w4a32_gemm<<<dim3(GN / BN, GM / BM), dim3(256), 0, stream>>>(A, S, Q, C);
  }
}

// Round 5
// 252.748 us; speedup vs baseline: 1.3006x; 1.1367x over previous
//
#include <hip/hip_runtime.h>
#include <stdint.h>

#define GM 4096
#define GN 4096
#define GK 4096
#define QW (GN/8)   /* 512 packed words per k-row */

typedef __attribute__((ext_vector_type(8))) short bf16x8;
typedef __attribute__((ext_vector_type(4))) float f32x4;

#define AS1 __attribute__((address_space(1)))
#define AS3 __attribute__((address_space(3)))

static __device__ __forceinline__ void glds16(const void* g, void* l) {
  __builtin_amdgcn_global_load_lds((const AS1 uint32_t*)g, (AS3 uint32_t*)l, 16, 0, 0);
}

static __device__ __forceinline__ uint32_t bf16pack_rn(float hi, float lo) {
  // round-half-up to bf16 (removes truncation bias; inputs are finite, |x|<1e3)
  uint32_t h = __float_as_uint(hi) + 0x8000u;
  uint32_t l = __float_as_uint(lo) + 0x8000u;
  return __builtin_amdgcn_perm(h, l, 0x07060302u);
}

// ---------------- Kernel 1: A fp32 -> bf16 (streaming, RN) ----------------
__global__ void __launch_bounds__(256) a_to_bf16(const float* __restrict__ A,
                                                 ushort* __restrict__ Ab) {
  size_t t = (size_t)blockIdx.x * 256 + threadIdx.x;
  const float4* p = (const float4*)(A + t * 8);
  float4 x = p[0], y = p[1];
  uint4 o;
  o.x = bf16pack_rn(x.y, x.x);
  o.y = bf16pack_rn(x.w, x.z);
  o.z = bf16pack_rn(y.y, y.x);
  o.w = bf16pack_rn(y.w, y.z);
  *(uint4*)(Ab + t * 8) = o;
}

// ------- Kernel 2: int4 dequant -> bf16 W^T [N][K] (LDS transpose, RN) -------
__global__ void __launch_bounds__(256) w_dequant(const float* __restrict__ S,
                                                 const uint32_t* __restrict__ Q,
                                                 ushort* __restrict__ Wt) {
  __shared__ __align__(16) ushort T[128 * 64];   // 16 KB
  const int tid = threadIdx.x;
  const int n0  = blockIdx.x * 128;
  const int k0  = blockIdx.y * 64;
  const int g   = k0 >> 7;                       // group (uniform: 64 | 128)

  #pragma unroll
  for (int c = 0; c < 2; ++c) {
    int idx = c * 256 + tid;
    int w   = idx & 15;                          // word col 0..15
    int k   = (idx >> 4) * 2;                    // even k 0..62
    uint32_t q0 = Q[(size_t)(k0 + k)     * QW + (n0 >> 3) + w];
    uint32_t q1 = Q[(size_t)(k0 + k + 1) * QW + (n0 >> 3) + w];
    const float* sp = S + (size_t)g * GN + n0 + w * 8;
    float4 sa = *(const float4*)sp, sb = *(const float4*)(sp + 4);
    float sv[8] = {sa.x, sa.y, sa.z, sa.w, sb.x, sb.y, sb.z, sb.w};
    const int swz = 8 * (w & 7);
    #pragma unroll
    for (int j = 0; j < 8; ++j) {
      float fa = (float)((q0 >> (4 * j)) & 0xFu);    // exact int->f32
      float fb = (float)((q1 >> (4 * j)) & 0xFu);
      float wa = fmaf(fa, sv[j], -8.0f * sv[j]);     // (nib-8)*s, 1 rounding
      float wb = fmaf(fb, sv[j], -8.0f * sv[j]);
      int n = w * 8 + j;
      *(uint32_t*)(&T[n * 64 + (k ^ swz)]) = bf16pack_rn(wb, wa);  // k=wa low
    }
  }
  __syncthreads();
  #pragma unroll
  for (int c = 0; c < 4; ++c) {
    int idx = c * 256 + tid;
    int n = idx >> 3, ko = idx & 7;
    int swz = (n >> 3) & 7;
    uint4 v = *(const uint4*)(&T[n * 64 + 8 * (ko ^ swz)]);
    *(uint4*)(&Wt[(size_t)(n0 + n) * GK + k0 + ko * 8]) = v;
  }
}

// ---------------- Kernel 3: bf16 GEMM ----------------
// 128x128x64 tiles, 256 threads (4 waves 2x2), 4x4 16x16x32 MFMA per wave.
// XOR-swizzled LDS (kb_phys = kb ^ (row&7)) -> conflict-free b128 reads
// (verified: SQ_LDS_BANK_CONFLICT = 0 in round 4).
// __launch_bounds__(256,4): cap regs at 128/wave so 4 blocks/CU are resident
// -> grid 1024 = 256 CU x 4 runs in ONE round (round-4 counters showed a
// 1.33-round tail wasting ~25%: occupancy 23.6% with 3 blocks/CU).
__global__ void __launch_bounds__(256, 4) gemm_bf16(const ushort* __restrict__ Ab,
                                                    const ushort* __restrict__ Wt,
                                                    float* __restrict__ C) {
  __shared__ __align__(16) ushort As[128 * 64];  // 16 KB
  __shared__ __align__(16) ushort Bs[128 * 64];  // 16 KB

  const int tid  = threadIdx.x;
  const int m0   = blockIdx.y * 128;
  const int n0   = blockIdx.x * 128;
  const int ln   = tid & 63;
  const int wid  = tid >> 6;
  const int wm   = (wid >> 1) * 64;
  const int wn   = (wid & 1) * 64;
  const int col  = ln & 15;
  const int quad = ln >> 4;
  const int srow = tid >> 3;                               // + c*32
  const int scol = (((tid & 7) ^ (srow & 7)) * 8);         // swizzled source chunk

  f32x4 acc[4][4];
  #pragma unroll
  for (int i = 0; i < 4; ++i)
    #pragma unroll
    for (int j = 0; j < 4; ++j)
      acc[i][j] = (f32x4){0.f, 0.f, 0.f, 0.f};

  const ushort* Abase = Ab + (size_t)m0 * GK + (size_t)srow * GK + scol;
  const ushort* Bbase = Wt + (size_t)n0 * GK + (size_t)srow * GK + scol;

  for (int k0 = 0; k0 < GK; k0 += 64) {
    #pragma unroll
    for (int c = 0; c < 4; ++c)
      glds16(Abase + (size_t)c * 32 * GK + k0, &As[(c * 256 + tid) * 8]);
    #pragma unroll
    for (int c = 0; c < 4; ++c)
      glds16(Bbase + (size_t)c * 32 * GK + k0, &Bs[(c * 256 + tid) * 8]);

    __syncthreads();   // drains vmcnt, LDS tiles ready

    #pragma unroll
    for (int kk = 0; kk < 2; ++kk) {
      const int kbA = (kk * 4 + quad) ^ (col & 7);         // swizzled k-block
      bf16x8 af[4], bfr[4];
      #pragma unroll
      for (int t = 0; t < 4; ++t) {
        af[t]  = *(const bf16x8*)(&As[(wm + t * 16 + col) * 64 + kbA * 8]);
        bfr[t] = *(const bf16x8*)(&Bs[(wn + t * 16 + col) * 64 + kbA * 8]);
      }
      #pragma unroll
      for (int mt = 0; mt < 4; ++mt)
        #pragma unroll
        for (int nt = 0; nt < 4; ++nt)
          acc[mt][nt] = __builtin_amdgcn_mfma_f32_16x16x32_bf16(
                            af[mt], bfr[nt], acc[mt][nt], 0, 0, 0);
    }

    __syncthreads();   // all reads done before next stage overwrites
  }

  // epilogue: C/D layout col=lane&15, row=quad*4+reg (m89)
  #pragma unroll
  for (int mt = 0; mt < 4; ++mt)
    #pragma unroll
    for (int nt = 0; nt < 4; ++nt)
      #pragma unroll
      for (int r = 0; r < 4; ++r)
        C[(size_t)(m0 + wm + mt * 16 + quad * 4 + r) * GN
          + n0 + wn + nt * 16 + col] = acc[mt][nt][r];
}

// ---------------- Fallback: fused dequant GEMM (round-2 kernel) ----------------
#define BM 128
#define BN 128
#define BK 32

__global__ void __launch_bounds__(256) w4a32_gemm(
    const float* __restrict__ A,
    const float* __restrict__ S,
    const uint32_t* __restrict__ Q,
    float* __restrict__ C)
{
  __shared__ __align__(16) ushort As[BM*BK];
  __shared__ __align__(16) ushort Bs[BN*BK];

  const int tid  = threadIdx.x;
  const int m0   = blockIdx.y*BM;
  const int n0   = blockIdx.x*BN;
  const int wcol  = tid & 15;
  const int kpair = tid >> 4;
  const int ln   = tid & 63;
  const int wid  = tid >> 6;
  const int wm   = (wid >> 1) * 64;
  const int wn   = (wid & 1) * 64;
  const int col  = ln & 15;
  const int quad = ln >> 4;

  f32x4 acc[4][4];
  #pragma unroll
  for (int i=0;i<4;++i)
    #pragma unroll
    for (int j=0;j<4;++j)
      acc[i][j] = (f32x4){0.f,0.f,0.f,0.f};

  float sv[8], cv[8];
  float4 spf0, spf1;

  const float*    Abase = A + (size_t)m0 * GK;
  const uint32_t* Qbase = Q + (size_t)(n0>>3) + wcol;

  {
    const float* sp = S + n0 + wcol*8;
    spf0 = *(const float4*)sp;
    spf1 = *(const float4*)(sp + 4);
  }

  float4 a4[4];
  uint32_t wqa, wqb;
  #pragma unroll
  for (int i=0;i<4;++i) {
    int f = tid + i*256;
    a4[i] = *(const float4*)(Abase + (size_t)(f>>3)*GK + ((f&7)*4));
  }
  wqa = Qbase[(size_t)(2*kpair)   * QW];
  wqb = Qbase[(size_t)(2*kpair+1) * QW];

  for (int k0 = 0; k0 < GK; k0 += BK) {
    if ((k0 & 127) == 0) {
      sv[0]=spf0.x; sv[1]=spf0.y; sv[2]=spf0.z; sv[3]=spf0.w;
      sv[4]=spf1.x; sv[5]=spf1.y; sv[6]=spf1.z; sv[7]=spf1.w;
      #pragma unroll
      for (int j=0;j<8;++j) cv[j] = -8.0f * sv[j];
    }

    #pragma unroll
    for (int i=0;i<4;++i) {
      int f = tid + i*256;
      int row = f>>3, c4 = f&7;
      *(uint2*)(&As[row*BK + c4*4]) =
        make_uint2(bf16pack_rn(a4[i].y, a4[i].x), bf16pack_rn(a4[i].w, a4[i].z));
    }

    {
      const int kk = (2*kpair) ^ (8*(wcol&3));
      #pragma unroll
      for (int j=0;j<8;++j) {
        float fa = (float)((wqa >> (4*j)) & 0xFu);
        float fb = (float)((wqb >> (4*j)) & 0xFu);
        float wa = fmaf(fa, sv[j], cv[j]);
        float wb = fmaf(fb, sv[j], cv[j]);
        int n = wcol*8 + j;
        *(uint32_t*)(&Bs[n*BK + kk]) = bf16pack_rn(wb, wa);
      }
    }

    int kn = k0 + BK; if (kn >= GK) kn = 0;
    if ((kn & 127) == 0) {
      const float* sp = S + (size_t)(kn>>7)*GN + n0 + wcol*8;
      spf0 = *(const float4*)sp;
      spf1 = *(const float4*)(sp + 4);
    }
    #pragma unroll
    for (int i=0;i<4;++i) {
      int f = tid + i*256;
      a4[i] = *(const float4*)(Abase + (size_t)(f>>3)*GK + kn + ((f&7)*4));
    }
    wqa = Qbase[(size_t)(kn + 2*kpair)   * QW];
    wqb = Qbase[(size_t)(kn + 2*kpair+1) * QW];

    __syncthreads();

    bf16x8 af[4], bfr[4];
    #pragma unroll
    for (int t=0;t<4;++t) {
      af[t] = *(const bf16x8*)(&As[(wm + t*16 + col)*BK + quad*8]);
      int n = wn + t*16 + col;
      int kk = (quad*8) ^ (8*((n>>3)&3));
      bfr[t] = *(const bf16x8*)(&Bs[n*BK + kk]);
    }
    #pragma unroll
    for (int mt=0;mt<4;++mt)
      #pragma unroll
      for (int nt=0;nt<4;++nt)
        acc[mt][nt] = __builtin_amdgcn_mfma_f32_16x16x32_bf16(
                          af[mt], bfr[nt], acc[mt][nt], 0, 0, 0);

    __syncthreads();
  }

  #pragma unroll
  for (int mt=0;mt<4;++mt)
    #pragma unroll
    for (int nt=0;nt<4;++nt)
      #pragma unroll
      for (int r=0;r<4;++r)
        C[(size_t)(m0 + wm + mt*16 + quad*4 + r)*GN + n0 + wn + nt*16 + col]
          = acc[mt][nt][r];
}

extern "C" void kernel_launch(void* const* d_in, const int* in_sizes, int n_in,
                              void* d_out, int out_size, void* d_ws, size_t ws_size,
                              hipStream_t stream) {
  const float*    A = (const float*)d_in[0];
  const float*    S = (const float*)d_in[1];
  const uint32_t* Q = (const uint32_t*)d_in[2];
  float*          C = (float*)d_out;

  const size_t need = (size_t)GM * GK * 2 + (size_t)GN * GK * 2;  // 64 MB
  if (ws_size >= need) {
    ushort* Abf = (ushort*)d_ws;                       // [M][K] bf16
    ushort* Wt  = (ushort*)d_ws + (size_t)GM * GK;     // [N][K] bf16 (W^T)
    a_to_bf16<<<dim3(GM * GK / (8 * 256)), dim3(256), 0, stream>>>(A, Abf);
    w_dequant<<<dim3(GN / 128, GK / 64), dim3(256), 0, stream>>>(S, Q, Wt);
    gemm_bf16<<<dim3(GN / 128, GM / 128), dim3(256), 0, stream>>>(Abf, Wt, C);
  } else {
    w4a32_gemm<<<dim3(GN / BN, GM / BM), dim3(256), 0, stream>>>(A, S, Q, C);
  }
}